// Round 6
// baseline (246.174 us; speedup 1.0000x reference)
//
#include <hip/hip_runtime.h>

#define N 1024
#define NN (N * N)
#define STRIPS 9           // strips of 128 cols (120 valid): 9*120 = 1080 >= 1024
#define SEGS 64
#define SEGROWS 16
#define NWAVES (STRIPS * SEGS * 8)   // 4608 waves (1 per block)

__device__ __forceinline__ int refl(int i) {   // reflect-101
    if (i < 0) return -i;
    if (i >= N) return 2 * N - 2 - i;
    return i;
}
__device__ __forceinline__ float shl(float v, int sl) { return __shfl(v, sl, 64); }

struct F2 { float x, y; };

__device__ __forceinline__ int axcode(float gx, float gy) {
    float ax = fabsf(gx), ay = fabsf(gy);
    return (ay <= 0.41421356f * ax) ? 0
         : (ay >= 2.41421356f * ax) ? 1
         : (((gx > 0.f) == (gy > 0.f)) ? 2 : 3);
}

__device__ __forceinline__ float pick(int code, float r, float u, float ur, float ul) {
    return code == 0 ? r : code == 1 ? u : code == 2 ? ur : ul;
}

template<bool EC>
__device__ __forceinline__ int strip_body(const float* __restrict__ A,
                                          const float* __restrict__ B,
                                          int cb, int R0, int lane)
{
    const float w0 = 0.05448868f, w1 = 0.24420134f, w2 = 0.40261996f,
                w3 = 0.24420134f, w4 = 0.05448868f;
    const int c0 = cb + 2 * lane, c1 = c0 + 1;
    const int lm = lane - 1, lp = lane + 1;
    const int cR0 = refl(c0), cR1 = refl(c1);
    const bool p0 = (c0 == 0);          // lane's .x is image col 0
    const bool pN = (c1 == N - 1);      // lane's .y is image col N-1
    const bool v0 = (lane >= 2 && lane <= 61 && c0 >= 0 && c0 < N);
    const bool v1 = (lane >= 2 && lane <= 61 && c1 < N);

    F2 ha0{},ha1{},ha2{},ha3{},ha4{}, hb0{},hb1{},hb2{},hb3{},hb4{};
    F2 bla0{},bla1{},bla2{}, blb0{},blb1{},blb2{};
    F2 mga0{},mga1{},mga2{}, mgla0{},mgla1{},mgla2{}, mgra0{},mgra1{},mgra2{};
    F2 mgb0{},mgb1{},mgb2{}, mglb0{},mglb1{},mglb2{}, mgrb0{},mgrb1{},mgrb2{};
    int axax = 0, axay = 0, axbx = 0, axby = 0;

    int acc = 0;

#pragma unroll 4
    for (int y = R0 - 4; y <= R0 + SEGROWS + 3; ++y) {   // 24 iterations
        const int rr = refl(y);
        F2 ga, gb;
        if (EC) {
            const float* pa0 = A + (size_t)rr * N + cR0;
            const float* pa1 = A + (size_t)rr * N + cR1;
            const float* pb0 = B + (size_t)rr * N + cR0;
            const float* pb1 = B + (size_t)rr * N + cR1;
            ga.x = 0.299f*pa0[0] + 0.587f*pa0[NN] + 0.114f*pa0[2*NN];
            ga.y = 0.299f*pa1[0] + 0.587f*pa1[NN] + 0.114f*pa1[2*NN];
            gb.x = 0.299f*pb0[0] + 0.587f*pb0[NN] + 0.114f*pb0[2*NN];
            gb.y = 0.299f*pb1[0] + 0.587f*pb1[NN] + 0.114f*pb1[2*NN];
        } else {
            const float* pa = A + (size_t)rr * N + c0;
            const float* pb = B + (size_t)rr * N + c0;
            float2 r  = *(const float2*)pa;
            float2 g  = *(const float2*)(pa + NN);
            float2 bb = *(const float2*)(pa + 2 * NN);
            ga.x = 0.299f*r.x + 0.587f*g.x + 0.114f*bb.x;
            ga.y = 0.299f*r.y + 0.587f*g.y + 0.114f*bb.y;
            r  = *(const float2*)pb;
            g  = *(const float2*)(pb + NN);
            bb = *(const float2*)(pb + 2 * NN);
            gb.x = 0.299f*r.x + 0.587f*g.x + 0.114f*bb.x;
            gb.y = 0.299f*r.y + 0.587f*g.y + 0.114f*bb.y;
        }

        // ---- horizontal blur: cols c-2,c-1 live in lane-1; c+1,c+2 in own/.lane+1
        float gaLx = shl(ga.x, lm), gaLy = shl(ga.y, lm);
        float gaRx = shl(ga.x, lp), gaRy = shl(ga.y, lp);
        float gbLx = shl(gb.x, lm), gbLy = shl(gb.y, lm);
        float gbRx = shl(gb.x, lp), gbRy = shl(gb.y, lp);
        F2 hna, hnb;
        hna.x = w0*gaLx + w1*gaLy + w2*ga.x + w3*ga.y + w4*gaRx;
        hna.y = w0*gaLy + w1*ga.x + w2*ga.y + w3*gaRx + w4*gaRy;
        hnb.x = w0*gbLx + w1*gbLy + w2*gb.x + w3*gb.y + w4*gbRx;
        hnb.y = w0*gbLy + w1*gb.x + w2*gb.y + w3*gbRx + w4*gbRy;
        ha0=ha1; ha1=ha2; ha2=ha3; ha3=ha4; ha4=hna;
        hb0=hb1; hb1=hb2; hb2=hb3; hb3=hb4; hb4=hnb;

        // ---- vertical blur -> blurred row y-2
        F2 bna, bnb;
        bna.x = w0*ha0.x + w1*ha1.x + w2*ha2.x + w3*ha3.x + w4*ha4.x;
        bna.y = w0*ha0.y + w1*ha1.y + w2*ha2.y + w3*ha3.y + w4*ha4.y;
        bnb.x = w0*hb0.x + w1*hb1.x + w2*hb2.x + w3*hb3.x + w4*hb4.x;
        bnb.y = w0*hb0.y + w1*hb1.y + w2*hb2.y + w3*hb3.y + w4*hb4.y;
        bla0=bla1; bla1=bla2; bla2=bna;
        blb0=blb1; blb1=blb2; blb2=bnb;

        // ---- Sobel rows at z = y-3 (row clamp is wave-uniform, rare)
        const int z = y - 3;
        F2 bA0 = bla0, bA2 = bla2, bB0 = blb0, bB2 = blb2;
        if (z == 0)     { bA0 = bla1; bB0 = blb1; }
        if (z == N - 1) { bA2 = bla1; bB2 = blb1; }
        F2 sa, da, sb, db;
        sa.x = bA0.x + 2.f*bla1.x + bA2.x;  sa.y = bA0.y + 2.f*bla1.y + bA2.y;
        da.x = bA2.x - bA0.x;               da.y = bA2.y - bA0.y;
        sb.x = bB0.x + 2.f*blb1.x + bB2.x;  sb.y = bB0.y + 2.f*blb1.y + bB2.y;
        db.x = bB2.x - bB0.x;               db.y = bB2.y - bB0.y;

        float saLy = shl(sa.y, lm), saRx = shl(sa.x, lp);
        float daLy = shl(da.y, lm), daRx = shl(da.x, lp);
        float sbLy = shl(sb.y, lm), sbRx = shl(sb.x, lp);
        float dbLy = shl(db.y, lm), dbRx = shl(db.x, lp);
        if (EC) {   // column edge-clamp (mode='edge') fixups
            saLy = p0 ? sa.x : saLy;  daLy = p0 ? da.x : daLy;
            sbLy = p0 ? sb.x : sbLy;  dbLy = p0 ? db.x : dbLy;
            saRx = pN ? sa.y : saRx;  daRx = pN ? da.y : daRx;
            sbRx = pN ? sb.y : sbRx;  dbRx = pN ? db.y : dbRx;
        }
        F2 gxa, gya, gxb, gyb;
        gxa.x = sa.y - saLy;              gxa.y = saRx - sa.x;
        gya.x = daLy + 2.f*da.x + da.y;   gya.y = da.x + 2.f*da.y + daRx;
        gxb.x = sb.y - sbLy;              gxb.y = sbRx - sb.x;
        gyb.x = dbLy + 2.f*db.x + db.y;   gyb.y = db.x + 2.f*db.y + dbRx;

        F2 maga, magb;
        maga.x = sqrtf(gxa.x*gxa.x + gya.x*gya.x + 1e-6f);
        maga.y = sqrtf(gxa.y*gxa.y + gya.y*gya.y + 1e-6f);
        magb.x = sqrtf(gxb.x*gxb.x + gyb.x*gyb.x + 1e-6f);
        magb.y = sqrtf(gxb.y*gxb.y + gyb.y*gyb.y + 1e-6f);

        int cax = axcode(gxa.x, gya.x), cay = axcode(gxa.y, gya.y);
        int cbx = axcode(gxb.x, gyb.x), cby = axcode(gxb.y, gyb.y);

        float maLy = shl(maga.y, lm), maRx = shl(maga.x, lp);
        float mbLy = shl(magb.y, lm), mbRx = shl(magb.x, lp);
        if (EC) {   // NMS conv zero-pads outside image
            maLy = p0 ? 0.f : maLy;  mbLy = p0 ? 0.f : mbLy;
            maRx = pN ? 0.f : maRx;  mbRx = pN ? 0.f : mbRx;
        }
        F2 mla{maLy, maga.x}, mra{maga.y, maRx};
        F2 mlb{mbLy, magb.x}, mrb{magb.y, mbRx};

        mga0=mga1;   mga1=mga2;   mga2=maga;
        mgla0=mgla1; mgla1=mgla2; mgla2=mla;
        mgra0=mgra1; mgra1=mgra2; mgra2=mra;
        mgb0=mgb1;   mgb1=mgb2;   mgb2=magb;
        mglb0=mglb1; mglb1=mglb2; mglb2=mlb;
        mgrb0=mgrb1; mgrb1=mgrb2; mgrb2=mrb;

        const int axUax = axax, axUay = axay, axUbx = axbx, axUby = axby;
        axax = cax; axay = cay; axbx = cbx; axby = cby;

        // ---- NMS + threshold at row w = y-4
        if (y >= R0 + 4) {
            const int w = y - 4;
            F2 upA=mga0, upLA=mgla0, upRA=mgra0, dnA=mga2, dnLA=mgla2, dnRA=mgra2;
            F2 upB=mgb0, upLB=mglb0, upRB=mgrb0, dnB=mgb2, dnLB=mglb2, dnRB=mgrb2;
            if (w == 0) {        // wave-uniform, only seg 0
                upA = F2{0,0}; upLA = F2{0,0}; upRA = F2{0,0};
                upB = F2{0,0}; upLB = F2{0,0}; upRB = F2{0,0};
            }
            if (w == N - 1) {    // only last seg
                dnA = F2{0,0}; dnLA = F2{0,0}; dnRA = F2{0,0};
                dnB = F2{0,0}; dnLB = F2{0,0}; dnRB = F2{0,0};
            }
            float n1ax = pick(axUax, mgra1.x, upA.x, upRA.x, upLA.x);
            float n2ax = pick(axUax, mgla1.x, dnA.x, dnLA.x, dnRA.x);
            float n1ay = pick(axUay, mgra1.y, upA.y, upRA.y, upLA.y);
            float n2ay = pick(axUay, mgla1.y, dnA.y, dnLA.y, dnRA.y);
            float n1bx = pick(axUbx, mgrb1.x, upB.x, upRB.x, upLB.x);
            float n2bx = pick(axUbx, mglb1.x, dnB.x, dnLB.x, dnRB.x);
            float n1by = pick(axUby, mgrb1.y, upB.y, upRB.y, upLB.y);
            float n2by = pick(axUby, mglb1.y, dnB.y, dnLB.y, dnRB.y);
            bool eax = (mga1.x > n1ax) && (mga1.x > n2ax) && (mga1.x > 0.1f);
            bool eay = (mga1.y > n1ay) && (mga1.y > n2ay) && (mga1.y > 0.1f);
            bool ebx = (mgb1.x > n1bx) && (mgb1.x > n2bx) && (mgb1.x > 0.1f);
            bool eby = (mgb1.y > n1by) && (mgb1.y > n2by) && (mgb1.y > 0.1f);
            acc += (int)(v0 && (eax != ebx));
            acc += (int)(v1 && (eay != eby));
        }
    }
    return acc;
}

__global__ __launch_bounds__(64)
void edge_diff_kernel(const float* __restrict__ op, const float* __restrict__ gt,
                      unsigned int* __restrict__ partials)
{
    int b = blockIdx.x;
    int img   = b / (STRIPS * SEGS);
    int rem   = b - img * (STRIPS * SEGS);
    int strip = rem / SEGS;
    int seg   = rem - strip * SEGS;
    int lane  = threadIdx.x;

    int cb = strip * 120 - 4;       // valid output cols: cb+4 .. cb+123
    int R0 = seg * SEGROWS;
    const float* A = op + (size_t)img * 3 * NN;
    const float* B = gt + (size_t)img * 3 * NN;

    int acc;
    if (strip == 0 || strip == STRIPS - 1)
        acc = strip_body<true>(A, B, cb, R0, lane);
    else
        acc = strip_body<false>(A, B, cb, R0, lane);

    for (int off = 32; off > 0; off >>= 1)
        acc += __shfl_down(acc, off, 64);
    if (lane == 0) partials[b] = (unsigned int)acc;
}

__global__ __launch_bounds__(256)
void finalize_kernel(const unsigned int* __restrict__ partials, float* __restrict__ out)
{
    __shared__ unsigned int ws[4];
    int tid = threadIdx.x;
    unsigned int sum = 0;
    for (int i = tid; i < NWAVES; i += 256)
        sum += partials[i];
    int d = (int)sum;
    for (int off = 32; off > 0; off >>= 1)
        d += __shfl_down(d, off, 64);
    if ((tid & 63) == 0) ws[tid >> 6] = (unsigned int)d;
    __syncthreads();
    if (tid == 0)
        out[0] = (float)(ws[0] + ws[1] + ws[2] + ws[3]) / 8388608.0f;  // 8*1024*1024
}

extern "C" void kernel_launch(void* const* d_in, const int* in_sizes, int n_in,
                              void* d_out, int out_size, void* d_ws, size_t ws_size,
                              hipStream_t stream)
{
    const float* op = (const float*)d_in[0];
    const float* gt = (const float*)d_in[1];
    unsigned int* partials = (unsigned int*)d_ws;   // NWAVES uints, fully overwritten

    edge_diff_kernel<<<dim3(NWAVES), dim3(64), 0, stream>>>(op, gt, partials);
    finalize_kernel<<<1, dim3(256), 0, stream>>>(partials, (float*)d_out);
}